// Round 7
// baseline (321.755 us; speedup 1.0000x reference)
//
#include <hip/hip_runtime.h>
#include <hip/hip_bf16.h>
#include <math.h>

#define NN 100000      // nodes
#define NE 1600000     // edges
#define NF 256         // input features
#define NH 128         // hidden
#define NC 40          // classes
#define NCP 64         // padded classes for W2t (rows >=40 zero)

#define NBINS     ((NN + 255) / 256)    // 391
#define BIN_CAP   5120                  // mean bin load 4096, sd~64 -> 16-sigma safe
#define CHUNK_A   4096
#define NB_A      ((NE + CHUNK_A - 1) / CHUNK_A)       // 391
#define GEMM1_NB  ((NN + 127) / 128)    // 782

// Workspace layout (4-byte units):
//   offr       [0,       200000)   int2 per node {beg,end} into erec4
//   bin_cursor [200128,  200519)
//   dinv       [300160,  400160)
//   H          [3600192, 10000192) (bf16 NN*NH)
//   w1t        [10000192,10016576) (bf16 [128][256])
//   w2t        [10016576,10020672) (bf16 [64][128], rows >=40 zero)
//   ebin       [16400192,18402112) (NBINS*BIN_CAP ints, dead after buildK2)
//   erec4      [18402112,20404032) (NBINS*BIN_CAP ints: src per edge)
//   H2a        [20404032,22004032) (bf16 [NN][32], classes 0-31: one 64B line/row)
//   H2b        [22004032,22404032) (bf16 [NN][8],  classes 32-39: 1.6MB, L2-resident)
#define OFF_CURSOR  200128
#define OFF_DINV    300160
#define OFF_H       3600192
#define OFF_W1T     10000192
#define OFF_W2T     10016576
#define OFF_EBIN    16400192
#define OFF_EREC4   18402112
#define OFF_H2A     20404032
#define OFF_H2B     22004032

using f32x4  = __attribute__((ext_vector_type(4))) float;
using bf16x8 = __attribute__((ext_vector_type(8))) short;

// decode packed pair of bf16 (lo, hi) to fp32x2 — exact, pure bit ops
__device__ inline float2 cvt2(unsigned u) {
    float2 f;
    f.x = __uint_as_float(u << 16);
    f.y = __uint_as_float(u & 0xffff0000u);
    return f;
}

__device__ inline short bfbits(float f) {
    __hip_bfloat16 h = __float2bfloat16(f);
    return *reinterpret_cast<short*>(&h);
}

__device__ inline unsigned pk2(float lo, float hi) {
    return (unsigned)(unsigned short)bfbits(lo) | ((unsigned)(unsigned short)bfbits(hi) << 16);
}

// ---------------- K0: bin cursor bases + W1t/W2t prep ----------------
__global__ void initk(int* __restrict__ bin_cursor,
                      const float* __restrict__ W1, __hip_bfloat16* __restrict__ W1t,
                      const float* __restrict__ W2, __hip_bfloat16* __restrict__ W2t) {
    int t = blockIdx.x * blockDim.x + threadIdx.x;
    if (t < NBINS) bin_cursor[t] = t * BIN_CAP;
    if (t < NH * NF) {
        int n = t >> 8;
        int k = t & (NF - 1);
        W1t[t] = __float2bfloat16(W1[(size_t)k * NH + n]);
    }
    if (t < NCP * NH) {
        int n = t >> 7;
        int k = t & (NH - 1);
        W2t[t] = __float2bfloat16((n < NC) ? W2[(size_t)k * NC + n] : 0.f);
    }
}

// ---------------- K1: FUSED layer-1 MFMA GEMM (BK=64, XOR-swizzled LDS) + pass A ----------------
// Block pattern (3k blocks): b%3==1 -> passA chunk b/3; else gemm tile 2*(b/3)+(b%3==2)
// LDS 64KB (2 blocks/CU, thread-capped anyway). 4 K-iters (was 8): half the barrier drains.
// Swizzle (T2/G4): [128][64]bf16 rows are 128B => all 16 lanes of a quad hit one bank.
// Fix: chunk c stored at c^(row&7). gload_lds dest must be linear (rule #21), so the
// involution is applied to the per-lane GLOBAL source offset; ds_reads apply the same XOR.
__global__ __launch_bounds__(1024, 2) void gemm1_passA(
        const int* __restrict__ ei, int* __restrict__ bin_cursor,
        int* __restrict__ ebin,
        const float* __restrict__ X, const __hip_bfloat16* __restrict__ W1t,
        __hip_bfloat16* __restrict__ H) {
    __shared__ __align__(16) int smem[16384];   // 64 KB: As dbuf(32K)+Bs dbuf(32K) OR passA hist/rbase

    const int bi = blockIdx.x / 3;
    const int br = blockIdx.x % 3;

    if (br == 1) {
        // ---- pass A: partition 4096 edges into 256-node bins, run-coalesced writes ----
        int* hist  = smem;
        int* rbase = smem + NBINS;
        int e0 = bi * CHUNK_A;
        int e1 = e0 + CHUNK_A; if (e1 > NE) e1 = NE;
        for (int j = threadIdx.x; j < NBINS; j += 1024) hist[j] = 0;
        __syncthreads();
        for (int p = e0 + threadIdx.x; p < e1; p += 1024)
            atomicAdd(&hist[ei[NE + p] >> 8], 1);
        __syncthreads();
        for (int j = threadIdx.x; j < NBINS; j += 1024) {
            int c = hist[j];
            rbase[j] = c ? atomicAdd(&bin_cursor[j], c) : 0;
        }
        __syncthreads();
        for (int p = e0 + threadIdx.x; p < e1; p += 1024) {
            int s = ei[p];
            int d = ei[NE + p];
            int bb = d >> 8;
            int pos = atomicAdd(&rbase[bb], 1);
            if (pos < (bb + 1) * BIN_CAP)          // 16-sigma overflow guard
                ebin[pos] = s | ((d & 255) << 17);
        }
        return;
    }

    // ---- gemm1 path: H = bf16(x @ W1), 128x128 tile, 16 waves, BK=64 dbuf ----
    short* As = (short*)smem;            // 2 x [128][64] bf16 (8192 shorts/buffer), swizzled
    short* Bs = (short*)smem + 16384;    // 2 x [128][64] bf16, swizzled

    const int tid  = threadIdx.x;
    const int wave = tid >> 6;          // 0..15
    const int lane = tid & 63;
    const int quad = lane >> 4;
    const int l16  = lane & 15;
    const int wy = wave >> 1, wx = wave & 1;
    const int m0 = (bi * 2 + (br == 2 ? 1 : 0)) * 128;

    // thread -> phys LDS chunk tid: row = tid>>3, cphys = tid&7; logical chunk = cphys ^ (row&7)
    const int srow = tid >> 3;
    const int scl  = (tid & 7) ^ (srow & 7);
    int gr = m0 + srow; if (gr > NN - 1) gr = NN - 1;
    const float* xbase = X + (size_t)gr * NF + scl * 8;                  // 8 fp32 = one chunk
    const __hip_bfloat16* wbase = W1t + (size_t)srow * NF + scl * 8;     // 8 bf16 = one chunk
    const int ldst = tid * 8;   // shorts: linear 16B/lane LDS dest

    f32x4 acc[4] = {};

    auto stageB = [&](int d, int kk) {
        __builtin_amdgcn_global_load_lds(
            (const __attribute__((address_space(1))) void*)(wbase + kk),
            (__attribute__((address_space(3))) void*)&Bs[d * 8192 + ldst],
            16, 0, 0);
    };

    // prologue: buffer 0
    {
        f32x4 x0 = *(const f32x4*)xbase;
        f32x4 x1 = *(const f32x4*)(xbase + 4);
        stageB(0, 0);
        uint4 w;
        w.x = pk2(x0.x, x0.y); w.y = pk2(x0.z, x0.w);
        w.z = pk2(x1.x, x1.y); w.w = pk2(x1.z, x1.w);
        *reinterpret_cast<uint4*>(&As[ldst]) = w;
    }
    __syncthreads();

    int cur = 0;
    #pragma unroll
    for (int k0 = 0; k0 < NF; k0 += 64) {
        const bool more = (k0 + 64 < NF);
        f32x4 x0, x1;
        if (more) {
            x0 = *(const f32x4*)(xbase + k0 + 64);   // issue early: HBM latency hides under MFMA
            x1 = *(const f32x4*)(xbase + k0 + 68);
            stageB(cur ^ 1, k0 + 64);
        }

        #pragma unroll
        for (int ks = 0; ks < 2; ++ks) {
            const int ar = wy * 16 + l16;
            const int ac = (ks * 4 + quad) ^ (ar & 7);
            bf16x8 a_frag = *(const bf16x8*)&As[cur * 8192 + ar * 64 + ac * 8];
            #pragma unroll
            for (int ni = 0; ni < 4; ++ni) {
                const int brr = wx * 64 + ni * 16 + l16;
                const int bc  = (ks * 4 + quad) ^ (brr & 7);
                bf16x8 b_frag = *(const bf16x8*)&Bs[cur * 8192 + brr * 64 + bc * 8];
                acc[ni] = __builtin_amdgcn_mfma_f32_16x16x32_bf16(
                    a_frag, b_frag, acc[ni], 0, 0, 0);
            }
        }

        if (more) {
            uint4 w;
            w.x = pk2(x0.x, x0.y); w.y = pk2(x0.z, x0.w);
            w.z = pk2(x1.x, x1.y); w.w = pk2(x1.z, x1.w);
            *reinterpret_cast<uint4*>(&As[(cur ^ 1) * 8192 + ldst]) = w;
        }
        __syncthreads();   // drains Bs gload_lds (vmcnt 0) + As ds_writes; protects swap
        cur ^= 1;
    }

    #pragma unroll
    for (int v = 0; v < 4; ++v) {
        int r = m0 + wy * 16 + quad * 4 + v;
        if (r < NN) {
            #pragma unroll
            for (int ni = 0; ni < 4; ++ni) {
                int c = wx * 64 + ni * 16 + l16;
                H[(size_t)r * NH + c] = __float2bfloat16(acc[ni][v]);
            }
        }
    }
}

// ---------------- K2: per-bin count + scan + offr/dinv + counting sort ----------------
__global__ __launch_bounds__(1024) void buildK2(const int* __restrict__ ebin,
                                                const int* __restrict__ bin_cursor,
                                                int2* __restrict__ offr,
                                                float* __restrict__ dinv,
                                                int* __restrict__ erec4) {
    __shared__ int ecache[BIN_CAP];   // 20 KB
    __shared__ int hist[256];
    __shared__ int scn[256];
    __shared__ int wsum4[4];

    const int b   = blockIdx.x;
    const int tid = threadIdx.x;
    const int n0  = b << 8;
    const int nodes = (NN - n0 > 256) ? 256 : (NN - n0);
    const int base = b * BIN_CAP;
    int cnt = bin_cursor[b] - base;
    if (cnt > BIN_CAP) cnt = BIN_CAP;

    if (tid < 256) hist[tid] = 0;
    __syncthreads();

    // pass 1: cache segment in LDS + per-node histogram
    for (int p = tid; p < cnt; p += 1024) {
        int e = ebin[base + p];
        ecache[p] = e;
        atomicAdd(&hist[e >> 17], 1);
    }
    __syncthreads();

    // 256-wide exclusive scan (4 waves)
    int v = 0, s = 0;
    const int lane = tid & 63, wave = tid >> 6;
    if (tid < 256) {
        v = hist[tid];
        s = v;
        #pragma unroll
        for (int off = 1; off < 64; off <<= 1) {
            int u = __shfl_up(s, off, 64);
            if (lane >= off) s += u;
        }
        if (lane == 63) wsum4[wave] = s;
    }
    __syncthreads();
    if (tid == 0) {
        int a = 0;
        #pragma unroll
        for (int w = 0; w < 4; ++w) { int t = wsum4[w]; wsum4[w] = a; a += t; }
    }
    __syncthreads();
    if (tid < 256) {
        int excl = (s - v) + wsum4[wave];
        scn[tid] = excl;
        if (tid < nodes) {
            offr[n0 + tid] = make_int2(base + excl, base + excl + v);
            dinv[n0 + tid] = rsqrtf((float)v + 1.0f);   // +1 self loop
        }
    }
    __syncthreads();

    // pass 2: counting sort from LDS -> erec4 (src only; weight factorized into aggs)
    for (int p = tid; p < cnt; p += 1024) {
        int e = ecache[p];
        int dl = e >> 17;
        int pos = atomicAdd(&scn[dl], 1);
        if (pos < BIN_CAP) erec4[base + pos] = e & 0x1FFFF;
    }
}

// ---------------- FUSED: layer-1 gather (group-per-node) + layer-2 GEMM from LDS ----------------
// 1024 threads/block: 64 gather groups x 2 nodes; MFMA phase waves 0..7.
// Output split: H2a [NN][32] (classes 0-31, exactly one 64B line/row) + H2b [NN][8]
// (classes 32-39; 1.6MB table -> L2-resident in agg2). Classes 40-47 dropped (were zero).
__global__ __launch_bounds__(1024, 2) void agg1_gemm2(
        const int2* __restrict__ offr, const int* __restrict__ erec4,
        const float* __restrict__ dinv, const __hip_bfloat16* __restrict__ H,
        const float* __restrict__ b1, const __hip_bfloat16* __restrict__ W2t,
        __hip_bfloat16* __restrict__ H2a, __hip_bfloat16* __restrict__ H2b) {
    __shared__ __align__(16) short As[128 * 128];   // 32 KB swizzled Hagg tile
    const int tid  = threadIdx.x;
    const int wave = tid >> 6;      // 0..15
    const int lane = tid & 63;
    const int quad = lane >> 4;
    const int l16  = lane & 15;
    const int grp  = tid >> 4;      // 0..63 gather group
    const int m0   = blockIdx.x * 128;
    const char* Hb = (const char*)H;
    const unsigned lb = (unsigned)(l16 << 4);

    #pragma unroll 1
    for (int rd = 0; rd < 2; ++rd) {
        int nl = rd * 64 + grp;
        int node = m0 + nl;
        if (node < NN) {
            int2 be = offr[node];
            int beg = be.x, end = be.y;
            float dls = dinv[node];
            float ac[8] = {};
            for (int p = beg; p < end; p += 4) {
                int s0 = erec4[p];
                int s1 = (p + 1 < end) ? erec4[p + 1] : 0;
                int s2 = (p + 2 < end) ? erec4[p + 2] : 0;
                int s3 = (p + 3 < end) ? erec4[p + 3] : 0;
                float w0 = dinv[s0];
                float w1 = (p + 1 < end) ? dinv[s1] : 0.f;
                float w2 = (p + 2 < end) ? dinv[s2] : 0.f;
                float w3 = (p + 3 < end) ? dinv[s3] : 0.f;
                uint4 h0 = *(const uint4*)(Hb + (((unsigned)s0) << 8) + lb);
                uint4 h1 = *(const uint4*)(Hb + (((unsigned)s1) << 8) + lb);
                uint4 h2 = *(const uint4*)(Hb + (((unsigned)s2) << 8) + lb);
                uint4 h3 = *(const uint4*)(Hb + (((unsigned)s3) << 8) + lb);
                #define ACC8(hv, ww) { \
                    float2 q0 = cvt2(hv.x), q1 = cvt2(hv.y), q2 = cvt2(hv.z), q3 = cvt2(hv.w); \
                    ac[0] += q0.x * (ww); ac[1] += q0.y * (ww); \
                    ac[2] += q1.x * (ww); ac[3] += q1.y * (ww); \
                    ac[4] += q2.x * (ww); ac[5] += q2.y * (ww); \
                    ac[6] += q3.x * (ww); ac[7] += q3.y * (ww); }
                ACC8(h0, w0) ACC8(h1, w1) ACC8(h2, w2) ACC8(h3, w3)
                #undef ACC8
            }
            // scale by dinv[dst], add self loop + bias, relu -> bf16 row in LDS
            float sl = dls * dls;
            uint4 hs = *(const uint4*)(Hb + (((unsigned)node) << 8) + lb);
            float2 s0f = cvt2(hs.x), s1f = cvt2(hs.y), s2f = cvt2(hs.z), s3f = cvt2(hs.w);
            const float4* bb = reinterpret_cast<const float4*>(b1 + l16 * 8);
            float4 ba = bb[0], bc = bb[1];
            float o0 = fmaxf(ac[0] * dls + s0f.x * sl + ba.x, 0.f);
            float o1 = fmaxf(ac[1] * dls + s0f.y * sl + ba.y, 0.f);
            float o2 = fmaxf(ac[2] * dls + s1f.x * sl + ba.z, 0.f);
            float o3 = fmaxf(ac[3] * dls + s1f.y * sl + ba.w, 0.f);
            float o4 = fmaxf(ac[4] * dls + s2f.x * sl + bc.x, 0.f);
            float o5 = fmaxf(ac[5] * dls + s2f.y * sl + bc.y, 0.f);
            float o6 = fmaxf(ac[6] * dls + s3f.x * sl + bc.z, 0.f);
            float o7 = fmaxf(ac[7] * dls + s3f.y * sl + bc.w, 0.f);
            uint4 ov;
            ov.x = pk2(o0, o1);
            ov.y = pk2(o2, o3);
            ov.z = pk2(o4, o5);
            ov.w = pk2(o6, o7);
            unsigned cb = lb ^ (((unsigned)nl & 7u) << 4);   // XOR-swizzle (G4)
            *reinterpret_cast<uint4*>((char*)As + nl * 256 + cb) = ov;
        }
    }

    // ---- W2 fragments to registers (16KB, L2-hot; only MFMA waves need them) ----
    bf16x8 bfr[4][3];
    if (wave < 8) {
        #pragma unroll
        for (int ks = 0; ks < 4; ++ks)
            #pragma unroll
            for (int ni = 0; ni < 3; ++ni)
                bfr[ks][ni] = *(const bf16x8*)(W2t + (size_t)(ni * 16 + l16) * NH + ks * 32 + quad * 8);
    }

    __syncthreads();
    if (wave >= 8) return;

    // ---- phase 2: 128x48x128 MFMA from LDS, waves 0..7 x 16 rows ----
    f32x4 acc2[3] = {};
    #pragma unroll
    for (int ks = 0; ks < 4; ++ks) {
        int row = wave * 16 + l16;
        unsigned cb = ((unsigned)(ks * 64 + quad * 16)) ^ (((unsigned)row & 7u) << 4);
        bf16x8 afr = *(const bf16x8*)((const char*)As + row * 256 + cb);
        #pragma unroll
        for (int ni = 0; ni < 3; ++ni)
            acc2[ni] = __builtin_amdgcn_mfma_f32_16x16x32_bf16(
                afr, bfr[ks][ni], acc2[ni], 0, 0, 0);
    }

    #pragma unroll
    for (int v = 0; v < 4; ++v) {
        int r = m0 + wave * 16 + quad * 4 + v;
        if (r < NN) {
            #pragma unroll
            for (int ni = 0; ni < 2; ++ni)
                H2a[(size_t)r * 32 + ni * 16 + l16] = __float2bfloat16(acc2[ni][v]);
            if (l16 < 8)
                H2b[(size_t)r * 8 + l16] = __float2bfloat16(acc2[2][v]);
        }
    }
}

// ---------------- layer-2 gather (16 lanes/node, 8 edges in flight, split tables) + lsm ----------------
__global__ void agg2_lsm(const int2* __restrict__ offr, const int* __restrict__ erec4,
                         const float* __restrict__ dinv, const __hip_bfloat16* __restrict__ H2a,
                         const __hip_bfloat16* __restrict__ H2b,
                         const float* __restrict__ b2, float* __restrict__ out) {
    int node = (blockIdx.x * blockDim.x + threadIdx.x) >> 4;
    if (node >= NN) return;
    int l16 = threadIdx.x & 15;
    const bool inA = (l16 < 8);          // lanes 0-7: H2a (classes 0-31)
    const bool act = (l16 < 10);         // lanes 8-9: H2b (classes 32-39); 10-15 idle
    const char* tb = inA ? (const char*)H2a : (const char*)H2b;
    const unsigned rmul = inA ? 64u : 16u;
    const unsigned off  = inA ? (unsigned)(l16 * 8) : (unsigned)((l16 - 8) * 8);
    const uint2 zz = make_uint2(0u, 0u);
    float a0 = 0.f, a1 = 0.f, a2 = 0.f, a3 = 0.f;
    int2 be = offr[node];
    int beg = be.x, end = be.y;
    float di = dinv[node];
    for (int p = beg; p < end; p += 8) {
        int s[8]; float w[8]; uint2 h[8];
        #pragma unroll
        for (int j = 0; j < 8; ++j) s[j] = (p + j < end) ? erec4[p + j] : 0;
        #pragma unroll
        for (int j = 0; j < 8; ++j) w[j] = (p + j < end) ? dinv[s[j]] : 0.f;
        #pragma unroll
        for (int j = 0; j < 8; ++j) h[j] = act ? *(const uint2*)(tb + (unsigned)s[j] * rmul + off) : zz;
        #pragma unroll
        for (int j = 0; j < 8; ++j) {
            float2 q0 = cvt2(h[j].x), q1 = cvt2(h[j].y);
            a0 += q0.x * w[j]; a1 += q0.y * w[j];
            a2 += q1.x * w[j]; a3 += q1.y * w[j];
        }
    }
    float v0, v1, v2, v3;
    if (act) {   // classes l16*4 .. l16*4+3 (lanes 0-9 cover 0..39)
        float sl = di * di;
        uint2 hs = *(const uint2*)(tb + (unsigned)node * rmul + off);
        float2 s0f = cvt2(hs.x), s1f = cvt2(hs.y);
        float4 bb = *reinterpret_cast<const float4*>(b2 + l16 * 4);
        v0 = a0 * di + s0f.x * sl + bb.x;
        v1 = a1 * di + s0f.y * sl + bb.y;
        v2 = a2 * di + s1f.x * sl + bb.z;
        v3 = a3 * di + s1f.y * sl + bb.w;
    } else {
        v0 = v1 = v2 = v3 = -INFINITY;
    }
    float m = fmaxf(fmaxf(v0, v1), fmaxf(v2, v3));
    #pragma unroll
    for (int off2 = 8; off2; off2 >>= 1) m = fmaxf(m, __shfl_xor(m, off2, 64));
    float ex = expf(v0 - m) + expf(v1 - m) + expf(v2 - m) + expf(v3 - m);
    #pragma unroll
    for (int off2 = 8; off2; off2 >>= 1) ex += __shfl_xor(ex, off2, 64);
    float ls = logf(ex);
    if (act) {
        float4 o;
        o.x = v0 - m - ls; o.y = v1 - m - ls;
        o.z = v2 - m - ls; o.w = v3 - m - ls;
        *reinterpret_cast<float4*>(out + (size_t)node * NC + l16 * 4) = o;
    }
}

extern "C" void kernel_launch(void* const* d_in, const int* in_sizes, int n_in,
                              void* d_out, int out_size, void* d_ws, size_t ws_size,
                              hipStream_t stream) {
    const float* x  = (const float*)d_in[0];
    const int*   ei = (const int*)d_in[1];
    const float* W1 = (const float*)d_in[2];
    const float* b1 = (const float*)d_in[3];
    const float* W2 = (const float*)d_in[4];
    const float* b2 = (const float*)d_in[5];
    float* out = (float*)d_out;

    int* wsb = (int*)d_ws;
    int2*  offr       = (int2*)wsb;
    int*   bin_cursor = wsb + OFF_CURSOR;
    float* dinv       = (float*)(wsb + OFF_DINV);
    __hip_bfloat16* H   = (__hip_bfloat16*)(wsb + OFF_H);
    __hip_bfloat16* W1t = (__hip_bfloat16*)(wsb + OFF_W1T);
    __hip_bfloat16* W2t = (__hip_bfloat16*)(wsb + OFF_W2T);
    int* ebin  = wsb + OFF_EBIN;
    int* erec4 = wsb + OFF_EREC4;
    __hip_bfloat16* H2a = (__hip_bfloat16*)(wsb + OFF_H2A);
    __hip_bfloat16* H2b = (__hip_bfloat16*)(wsb + OFF_H2B);

    // K0: cursor bases + weight transposes
    initk<<<(NH * NF + 255) / 256, 256, 0, stream>>>(bin_cursor, W1, W1t, W2, W2t);

    // K1: gemm1 (MFMA, BK=64, swizzled LDS) interleaved with pass A binning
    gemm1_passA<<<GEMM1_NB + NB_A, 1024, 0, stream>>>(ei, bin_cursor, ebin, x, W1t, H);

    // K2: per-bin hist + scan + offr/dinv + counting sort -> erec4 (4B/edge)
    buildK2<<<NBINS, 1024, 0, stream>>>(ebin, bin_cursor, offr, dinv, erec4);

    // K3: FUSED layer-1 gather + layer-2 GEMM -> H2a/H2b (split tables)
    agg1_gemm2<<<(NN + 127) / 128, 1024, 0, stream>>>(offr, erec4, dinv, H, b1, W2t, H2a, H2b);

    // K4: layer-2 gather + self + bias + log_softmax -> out
    {
        long long threads = (long long)NN * 16;
        agg2_lsm<<<(unsigned)((threads + 255) / 256), 256, 0, stream>>>(
            offr, erec4, dinv, H2a, H2b, b2, out);
    }
}

// Round 8
// 321.253 us; speedup vs baseline: 1.0016x; 1.0016x over previous
//
#include <hip/hip_runtime.h>
#include <hip/hip_bf16.h>
#include <math.h>

#define NN 100000      // nodes
#define NE 1600000     // edges
#define NF 256         // input features
#define NH 128         // hidden
#define NC 40          // classes
#define NCP 64         // padded classes for W2t (rows >=40 zero)

#define NBINS     ((NN + 255) / 256)    // 391
#define BIN_CAP   5120                  // mean bin load 4096, sd~64 -> 16-sigma safe
#define CHUNK_A   4096
#define NB_A      ((NE + CHUNK_A - 1) / CHUNK_A)       // 391
#define GEMM1_NB  ((NN + 127) / 128)    // 782

// Workspace layout (4-byte units):
//   offr       [0,       200000)   int2 per node {beg,end} into erec4
//   bin_cursor [200128,  200519)
//   dinv       [300160,  400160)
//   H          [3600192, 10000192) (bf16 NN*NH)
//   w1t        [10000192,10016576) (bf16 [128][256])
//   w2t        [10016576,10020672) (bf16 [64][128], rows >=40 zero)
//   ebin       [16400192,18402112) (NBINS*BIN_CAP ints, dead after buildK2)
//   erec4      [18402112,20404032) (NBINS*BIN_CAP ints: src per edge)
//   H2a        [20404032,22004032) (bf16 [NN][32], classes 0-31: one 64B line/row)
//   H2b        [22004032,22404032) (bf16 [NN][8],  classes 32-39: 1.6MB, L2-resident)
#define OFF_CURSOR  200128
#define OFF_DINV    300160
#define OFF_H       3600192
#define OFF_W1T     10000192
#define OFF_W2T     10016576
#define OFF_EBIN    16400192
#define OFF_EREC4   18402112
#define OFF_H2A     20404032
#define OFF_H2B     22004032

using f32x4  = __attribute__((ext_vector_type(4))) float;
using bf16x8 = __attribute__((ext_vector_type(8))) short;

// decode packed pair of bf16 (lo, hi) to fp32x2 — exact, pure bit ops
__device__ inline float2 cvt2(unsigned u) {
    float2 f;
    f.x = __uint_as_float(u << 16);
    f.y = __uint_as_float(u & 0xffff0000u);
    return f;
}

__device__ inline short bfbits(float f) {
    __hip_bfloat16 h = __float2bfloat16(f);
    return *reinterpret_cast<short*>(&h);
}

__device__ inline unsigned pk2(float lo, float hi) {
    return (unsigned)(unsigned short)bfbits(lo) | ((unsigned)(unsigned short)bfbits(hi) << 16);
}

// ---------------- K0: bin cursor bases + W1t/W2t prep ----------------
__global__ void initk(int* __restrict__ bin_cursor,
                      const float* __restrict__ W1, __hip_bfloat16* __restrict__ W1t,
                      const float* __restrict__ W2, __hip_bfloat16* __restrict__ W2t) {
    int t = blockIdx.x * blockDim.x + threadIdx.x;
    if (t < NBINS) bin_cursor[t] = t * BIN_CAP;
    if (t < NH * NF) {
        int n = t >> 8;
        int k = t & (NF - 1);
        W1t[t] = __float2bfloat16(W1[(size_t)k * NH + n]);
    }
    if (t < NCP * NH) {
        int n = t >> 7;
        int k = t & (NH - 1);
        W2t[t] = __float2bfloat16((n < NC) ? W2[(size_t)k * NC + n] : 0.f);
    }
}

// ---------------- K1: FUSED layer-1 MFMA GEMM (BK=64, XOR-swizzled LDS) + pass A ----------------
// Block pattern (3k blocks): b%3==1 -> passA chunk b/3; else gemm tile 2*(b/3)+(b%3==2)
__global__ __launch_bounds__(1024, 2) void gemm1_passA(
        const int* __restrict__ ei, int* __restrict__ bin_cursor,
        int* __restrict__ ebin,
        const float* __restrict__ X, const __hip_bfloat16* __restrict__ W1t,
        __hip_bfloat16* __restrict__ H) {
    __shared__ __align__(16) int smem[16384];   // 64 KB: As dbuf(32K)+Bs dbuf(32K) OR passA hist/rbase

    const int bi = blockIdx.x / 3;
    const int br = blockIdx.x % 3;

    if (br == 1) {
        // ---- pass A: partition 4096 edges into 256-node bins, run-coalesced writes ----
        int* hist  = smem;
        int* rbase = smem + NBINS;
        int e0 = bi * CHUNK_A;
        int e1 = e0 + CHUNK_A; if (e1 > NE) e1 = NE;
        for (int j = threadIdx.x; j < NBINS; j += 1024) hist[j] = 0;
        __syncthreads();
        for (int p = e0 + threadIdx.x; p < e1; p += 1024)
            atomicAdd(&hist[ei[NE + p] >> 8], 1);
        __syncthreads();
        for (int j = threadIdx.x; j < NBINS; j += 1024) {
            int c = hist[j];
            rbase[j] = c ? atomicAdd(&bin_cursor[j], c) : 0;
        }
        __syncthreads();
        for (int p = e0 + threadIdx.x; p < e1; p += 1024) {
            int s = ei[p];
            int d = ei[NE + p];
            int bb = d >> 8;
            int pos = atomicAdd(&rbase[bb], 1);
            if (pos < (bb + 1) * BIN_CAP)          // 16-sigma overflow guard
                ebin[pos] = s | ((d & 255) << 17);
        }
        return;
    }

    // ---- gemm1 path: H = bf16(x @ W1), 128x128 tile, 16 waves, BK=64 dbuf ----
    short* As = (short*)smem;            // 2 x [128][64] bf16 (8192 shorts/buffer), swizzled
    short* Bs = (short*)smem + 16384;    // 2 x [128][64] bf16, swizzled

    const int tid  = threadIdx.x;
    const int wave = tid >> 6;          // 0..15
    const int lane = tid & 63;
    const int quad = lane >> 4;
    const int l16  = lane & 15;
    const int wy = wave >> 1, wx = wave & 1;
    const int m0 = (bi * 2 + (br == 2 ? 1 : 0)) * 128;

    // thread -> phys LDS chunk tid: row = tid>>3, cphys = tid&7; logical chunk = cphys ^ (row&7)
    const int srow = tid >> 3;
    const int scl  = (tid & 7) ^ (srow & 7);
    int gr = m0 + srow; if (gr > NN - 1) gr = NN - 1;
    const float* xbase = X + (size_t)gr * NF + scl * 8;                  // 8 fp32 = one chunk
    const __hip_bfloat16* wbase = W1t + (size_t)srow * NF + scl * 8;     // 8 bf16 = one chunk
    const int ldst = tid * 8;   // shorts: linear 16B/lane LDS dest

    f32x4 acc[4] = {};

    auto stageB = [&](int d, int kk) {
        __builtin_amdgcn_global_load_lds(
            (const __attribute__((address_space(1))) void*)(wbase + kk),
            (__attribute__((address_space(3))) void*)&Bs[d * 8192 + ldst],
            16, 0, 0);
    };

    // prologue: buffer 0
    {
        f32x4 x0 = *(const f32x4*)xbase;
        f32x4 x1 = *(const f32x4*)(xbase + 4);
        stageB(0, 0);
        uint4 w;
        w.x = pk2(x0.x, x0.y); w.y = pk2(x0.z, x0.w);
        w.z = pk2(x1.x, x1.y); w.w = pk2(x1.z, x1.w);
        *reinterpret_cast<uint4*>(&As[ldst]) = w;
    }
    __syncthreads();

    int cur = 0;
    #pragma unroll
    for (int k0 = 0; k0 < NF; k0 += 64) {
        const bool more = (k0 + 64 < NF);
        f32x4 x0, x1;
        if (more) {
            x0 = *(const f32x4*)(xbase + k0 + 64);   // issue early: HBM latency hides under MFMA
            x1 = *(const f32x4*)(xbase + k0 + 68);
            stageB(cur ^ 1, k0 + 64);
        }

        #pragma unroll
        for (int ks = 0; ks < 2; ++ks) {
            const int ar = wy * 16 + l16;
            const int ac = (ks * 4 + quad) ^ (ar & 7);
            bf16x8 a_frag = *(const bf16x8*)&As[cur * 8192 + ar * 64 + ac * 8];
            #pragma unroll
            for (int ni = 0; ni < 4; ++ni) {
                const int brr = wx * 64 + ni * 16 + l16;
                const int bc  = (ks * 4 + quad) ^ (brr & 7);
                bf16x8 b_frag = *(const bf16x8*)&Bs[cur * 8192 + brr * 64 + bc * 8];
                acc[ni] = __builtin_amdgcn_mfma_f32_16x16x32_bf16(
                    a_frag, b_frag, acc[ni], 0, 0, 0);
            }
        }

        if (more) {
            uint4 w;
            w.x = pk2(x0.x, x0.y); w.y = pk2(x0.z, x0.w);
            w.z = pk2(x1.x, x1.y); w.w = pk2(x1.z, x1.w);
            *reinterpret_cast<uint4*>(&As[(cur ^ 1) * 8192 + ldst]) = w;
        }
        __syncthreads();   // drains Bs gload_lds (vmcnt 0) + As ds_writes; protects swap
        cur ^= 1;
    }

    #pragma unroll
    for (int v = 0; v < 4; ++v) {
        int r = m0 + wy * 16 + quad * 4 + v;
        if (r < NN) {
            #pragma unroll
            for (int ni = 0; ni < 4; ++ni) {
                int c = wx * 64 + ni * 16 + l16;
                H[(size_t)r * NH + c] = __float2bfloat16(acc[ni][v]);
            }
        }
    }
}

// ---------------- K2: per-bin count + scan + offr/dinv + counting sort ----------------
__global__ __launch_bounds__(1024) void buildK2(const int* __restrict__ ebin,
                                                const int* __restrict__ bin_cursor,
                                                int2* __restrict__ offr,
                                                float* __restrict__ dinv,
                                                int* __restrict__ erec4) {
    __shared__ int ecache[BIN_CAP];   // 20 KB
    __shared__ int hist[256];
    __shared__ int scn[256];
    __shared__ int wsum4[4];

    const int b   = blockIdx.x;
    const int tid = threadIdx.x;
    const int n0  = b << 8;
    const int nodes = (NN - n0 > 256) ? 256 : (NN - n0);
    const int base = b * BIN_CAP;
    int cnt = bin_cursor[b] - base;
    if (cnt > BIN_CAP) cnt = BIN_CAP;

    if (tid < 256) hist[tid] = 0;
    __syncthreads();

    // pass 1: cache segment in LDS + per-node histogram
    for (int p = tid; p < cnt; p += 1024) {
        int e = ebin[base + p];
        ecache[p] = e;
        atomicAdd(&hist[e >> 17], 1);
    }
    __syncthreads();

    // 256-wide exclusive scan (4 waves)
    int v = 0, s = 0;
    const int lane = tid & 63, wave = tid >> 6;
    if (tid < 256) {
        v = hist[tid];
        s = v;
        #pragma unroll
        for (int off = 1; off < 64; off <<= 1) {
            int u = __shfl_up(s, off, 64);
            if (lane >= off) s += u;
        }
        if (lane == 63) wsum4[wave] = s;
    }
    __syncthreads();
    if (tid == 0) {
        int a = 0;
        #pragma unroll
        for (int w = 0; w < 4; ++w) { int t = wsum4[w]; wsum4[w] = a; a += t; }
    }
    __syncthreads();
    if (tid < 256) {
        int excl = (s - v) + wsum4[wave];
        scn[tid] = excl;
        if (tid < nodes) {
            offr[n0 + tid] = make_int2(base + excl, base + excl + v);
            dinv[n0 + tid] = rsqrtf((float)v + 1.0f);   // +1 self loop
        }
    }
    __syncthreads();

    // pass 2: counting sort from LDS -> erec4 (src only; weight factorized into aggs)
    for (int p = tid; p < cnt; p += 1024) {
        int e = ecache[p];
        int dl = e >> 17;
        int pos = atomicAdd(&scn[dl], 1);
        if (pos < BIN_CAP) erec4[base + pos] = e & 0x1FFFF;
    }
}

// ---------------- FUSED: layer-1 gather (group-per-node) + layer-2 GEMM from LDS ----------------
// 1024 threads/block: 64 gather groups x 2 nodes; MFMA phase waves 0..7.
__global__ __launch_bounds__(1024, 2) void agg1_gemm2(
        const int2* __restrict__ offr, const int* __restrict__ erec4,
        const float* __restrict__ dinv, const __hip_bfloat16* __restrict__ H,
        const float* __restrict__ b1, const __hip_bfloat16* __restrict__ W2t,
        __hip_bfloat16* __restrict__ H2a, __hip_bfloat16* __restrict__ H2b) {
    __shared__ __align__(16) short As[128 * 128];   // 32 KB swizzled Hagg tile
    const int tid  = threadIdx.x;
    const int wave = tid >> 6;      // 0..15
    const int lane = tid & 63;
    const int quad = lane >> 4;
    const int l16  = lane & 15;
    const int grp  = tid >> 4;      // 0..63 gather group
    const int m0   = blockIdx.x * 128;
    const char* Hb = (const char*)H;
    const unsigned lb = (unsigned)(l16 << 4);

    #pragma unroll 1
    for (int rd = 0; rd < 2; ++rd) {
        int nl = rd * 64 + grp;
        int node = m0 + nl;
        if (node < NN) {
            int2 be = offr[node];
            int beg = be.x, end = be.y;
            float dls = dinv[node];
            float ac[8] = {};
            for (int p = beg; p < end; p += 4) {
                int s0 = erec4[p];
                int s1 = (p + 1 < end) ? erec4[p + 1] : 0;
                int s2 = (p + 2 < end) ? erec4[p + 2] : 0;
                int s3 = (p + 3 < end) ? erec4[p + 3] : 0;
                float w0 = dinv[s0];
                float w1 = (p + 1 < end) ? dinv[s1] : 0.f;
                float w2 = (p + 2 < end) ? dinv[s2] : 0.f;
                float w3 = (p + 3 < end) ? dinv[s3] : 0.f;
                uint4 h0 = *(const uint4*)(Hb + (((unsigned)s0) << 8) + lb);
                uint4 h1 = *(const uint4*)(Hb + (((unsigned)s1) << 8) + lb);
                uint4 h2 = *(const uint4*)(Hb + (((unsigned)s2) << 8) + lb);
                uint4 h3 = *(const uint4*)(Hb + (((unsigned)s3) << 8) + lb);
                #define ACC8(hv, ww) { \
                    float2 q0 = cvt2(hv.x), q1 = cvt2(hv.y), q2 = cvt2(hv.z), q3 = cvt2(hv.w); \
                    ac[0] += q0.x * (ww); ac[1] += q0.y * (ww); \
                    ac[2] += q1.x * (ww); ac[3] += q1.y * (ww); \
                    ac[4] += q2.x * (ww); ac[5] += q2.y * (ww); \
                    ac[6] += q3.x * (ww); ac[7] += q3.y * (ww); }
                ACC8(h0, w0) ACC8(h1, w1) ACC8(h2, w2) ACC8(h3, w3)
                #undef ACC8
            }
            // scale by dinv[dst], add self loop + bias, relu -> bf16 row in LDS
            float sl = dls * dls;
            uint4 hs = *(const uint4*)(Hb + (((unsigned)node) << 8) + lb);
            float2 s0f = cvt2(hs.x), s1f = cvt2(hs.y), s2f = cvt2(hs.z), s3f = cvt2(hs.w);
            const float4* bb = reinterpret_cast<const float4*>(b1 + l16 * 8);
            float4 ba = bb[0], bc = bb[1];
            float o0 = fmaxf(ac[0] * dls + s0f.x * sl + ba.x, 0.f);
            float o1 = fmaxf(ac[1] * dls + s0f.y * sl + ba.y, 0.f);
            float o2 = fmaxf(ac[2] * dls + s1f.x * sl + ba.z, 0.f);
            float o3 = fmaxf(ac[3] * dls + s1f.y * sl + ba.w, 0.f);
            float o4 = fmaxf(ac[4] * dls + s2f.x * sl + bc.x, 0.f);
            float o5 = fmaxf(ac[5] * dls + s2f.y * sl + bc.y, 0.f);
            float o6 = fmaxf(ac[6] * dls + s3f.x * sl + bc.z, 0.f);
            float o7 = fmaxf(ac[7] * dls + s3f.y * sl + bc.w, 0.f);
            uint4 ov;
            ov.x = pk2(o0, o1);
            ov.y = pk2(o2, o3);
            ov.z = pk2(o4, o5);
            ov.w = pk2(o6, o7);
            unsigned cb = lb ^ (((unsigned)nl & 7u) << 4);   // XOR-swizzle (G4)
            *reinterpret_cast<uint4*>((char*)As + nl * 256 + cb) = ov;
        }
    }

    // ---- W2 fragments to registers (16KB, L2-hot; only MFMA waves need them) ----
    bf16x8 bfr[4][3];
    if (wave < 8) {
        #pragma unroll
        for (int ks = 0; ks < 4; ++ks)
            #pragma unroll
            for (int ni = 0; ni < 3; ++ni)
                bfr[ks][ni] = *(const bf16x8*)(W2t + (size_t)(ni * 16 + l16) * NH + ks * 32 + quad * 8);
    }

    __syncthreads();
    if (wave >= 8) return;

    // ---- phase 2: 128x48x128 MFMA from LDS, waves 0..7 x 16 rows ----
    f32x4 acc2[3] = {};
    #pragma unroll
    for (int ks = 0; ks < 4; ++ks) {
        int row = wave * 16 + l16;
        unsigned cb = ((unsigned)(ks * 64 + quad * 16)) ^ (((unsigned)row & 7u) << 4);
        bf16x8 afr = *(const bf16x8*)((const char*)As + row * 256 + cb);
        #pragma unroll
        for (int ni = 0; ni < 3; ++ni)
            acc2[ni] = __builtin_amdgcn_mfma_f32_16x16x32_bf16(
                afr, bfr[ks][ni], acc2[ni], 0, 0, 0);
    }

    #pragma unroll
    for (int v = 0; v < 4; ++v) {
        int r = m0 + wave * 16 + quad * 4 + v;
        if (r < NN) {
            #pragma unroll
            for (int ni = 0; ni < 2; ++ni)
                H2a[(size_t)r * 32 + ni * 16 + l16] = __float2bfloat16(acc2[ni][v]);
            if (l16 < 8)
                H2b[(size_t)r * 8 + l16] = __float2bfloat16(acc2[2][v]);
        }
    }
}

// ---------------- layer-2 gather: 8 lanes/node (full lane utilization) + log_softmax ----------------
// Lane l8 owns classes l8*4..+3 from H2a (8B of the 64B row). Lanes 0-1 additionally
// accumulate classes 32-39 from H2b (1.6MB, L2-resident). 4 edges in flight.
__global__ void agg2_lsm(const int2* __restrict__ offr, const int* __restrict__ erec4,
                         const float* __restrict__ dinv, const __hip_bfloat16* __restrict__ H2a,
                         const __hip_bfloat16* __restrict__ H2b,
                         const float* __restrict__ b2, float* __restrict__ out) {
    int node = (blockIdx.x * blockDim.x + threadIdx.x) >> 3;
    if (node >= NN) return;
    int l8 = threadIdx.x & 7;
    const bool sec = (l8 < 2);
    const char* Ha = (const char*)H2a;
    const char* Hb = (const char*)H2b;
    const unsigned offA = (unsigned)(l8 * 8);
    const uint2 zz = make_uint2(0u, 0u);
    float a0 = 0.f, a1 = 0.f, a2 = 0.f, a3 = 0.f;   // primary: classes l8*4..+3
    float c0 = 0.f, c1 = 0.f, c2 = 0.f, c3 = 0.f;   // secondary (lanes 0-1): 32+l8*4..+3
    int2 be = offr[node];
    int beg = be.x, end = be.y;
    float di = dinv[node];
    for (int p = beg; p < end; p += 4) {
        int s[4]; float w[4]; uint2 h[4], hb[4];
        #pragma unroll
        for (int j = 0; j < 4; ++j) s[j] = (p + j < end) ? erec4[p + j] : 0;
        #pragma unroll
        for (int j = 0; j < 4; ++j) w[j] = (p + j < end) ? dinv[s[j]] : 0.f;
        #pragma unroll
        for (int j = 0; j < 4; ++j) h[j] = *(const uint2*)(Ha + (unsigned)s[j] * 64u + offA);
        #pragma unroll
        for (int j = 0; j < 4; ++j) hb[j] = sec ? *(const uint2*)(Hb + (unsigned)s[j] * 16u + offA) : zz;
        #pragma unroll
        for (int j = 0; j < 4; ++j) {
            float2 q0 = cvt2(h[j].x), q1 = cvt2(h[j].y);
            a0 += q0.x * w[j]; a1 += q0.y * w[j];
            a2 += q1.x * w[j]; a3 += q1.y * w[j];
            float2 r0 = cvt2(hb[j].x), r1 = cvt2(hb[j].y);
            c0 += r0.x * w[j]; c1 += r0.y * w[j];
            c2 += r1.x * w[j]; c3 += r1.y * w[j];
        }
    }
    float sl = di * di;
    // primary logits
    float v0, v1, v2, v3;
    {
        uint2 hs = *(const uint2*)(Ha + (unsigned)node * 64u + offA);
        float2 s0f = cvt2(hs.x), s1f = cvt2(hs.y);
        float4 bb = *reinterpret_cast<const float4*>(b2 + l8 * 4);
        v0 = a0 * di + s0f.x * sl + bb.x;
        v1 = a1 * di + s0f.y * sl + bb.y;
        v2 = a2 * di + s1f.x * sl + bb.z;
        v3 = a3 * di + s1f.y * sl + bb.w;
    }
    // secondary logits (lanes 0-1)
    float u0 = -INFINITY, u1 = -INFINITY, u2 = -INFINITY, u3 = -INFINITY;
    if (sec) {
        uint2 hs = *(const uint2*)(Hb + (unsigned)node * 16u + offA);
        float2 s0f = cvt2(hs.x), s1f = cvt2(hs.y);
        float4 bb = *reinterpret_cast<const float4*>(b2 + 32 + l8 * 4);
        u0 = c0 * di + s0f.x * sl + bb.x;
        u1 = c1 * di + s0f.y * sl + bb.y;
        u2 = c2 * di + s1f.x * sl + bb.z;
        u3 = c3 * di + s1f.y * sl + bb.w;
    }
    float m = fmaxf(fmaxf(v0, v1), fmaxf(v2, v3));
    if (sec) m = fmaxf(m, fmaxf(fmaxf(u0, u1), fmaxf(u2, u3)));
    #pragma unroll
    for (int off2 = 4; off2; off2 >>= 1) m = fmaxf(m, __shfl_xor(m, off2, 64));
    float ex = expf(v0 - m) + expf(v1 - m) + expf(v2 - m) + expf(v3 - m);
    if (sec) ex += expf(u0 - m) + expf(u1 - m) + expf(u2 - m) + expf(u3 - m);
    #pragma unroll
    for (int off2 = 4; off2; off2 >>= 1) ex += __shfl_xor(ex, off2, 64);
    float ls = logf(ex);
    {
        float4 o;
        o.x = v0 - m - ls; o.y = v1 - m - ls;
        o.z = v2 - m - ls; o.w = v3 - m - ls;
        *reinterpret_cast<float4*>(out + (size_t)node * NC + l8 * 4) = o;
    }
    if (sec) {
        float4 o;
        o.x = u0 - m - ls; o.y = u1 - m - ls;
        o.z = u2 - m - ls; o.w = u3 - m - ls;
        *reinterpret_cast<float4*>(out + (size_t)node * NC + 32 + l8 * 4) = o;
    }
}

extern "C" void kernel_launch(void* const* d_in, const int* in_sizes, int n_in,
                              void* d_out, int out_size, void* d_ws, size_t ws_size,
                              hipStream_t stream) {
    const float* x  = (const float*)d_in[0];
    const int*   ei = (const int*)d_in[1];
    const float* W1 = (const float*)d_in[2];
    const float* b1 = (const float*)d_in[3];
    const float* W2 = (const float*)d_in[4];
    const float* b2 = (const float*)d_in[5];
    float* out = (float*)d_out;

    int* wsb = (int*)d_ws;
    int2*  offr       = (int2*)wsb;
    int*   bin_cursor = wsb + OFF_CURSOR;
    float* dinv       = (float*)(wsb + OFF_DINV);
    __hip_bfloat16* H   = (__hip_bfloat16*)(wsb + OFF_H);
    __hip_bfloat16* W1t = (__hip_bfloat16*)(wsb + OFF_W1T);
    __hip_bfloat16* W2t = (__hip_bfloat16*)(wsb + OFF_W2T);
    int* ebin  = wsb + OFF_EBIN;
    int* erec4 = wsb + OFF_EREC4;
    __hip_bfloat16* H2a = (__hip_bfloat16*)(wsb + OFF_H2A);
    __hip_bfloat16* H2b = (__hip_bfloat16*)(wsb + OFF_H2B);

    // K0: cursor bases + weight transposes
    initk<<<(NH * NF + 255) / 256, 256, 0, stream>>>(bin_cursor, W1, W1t, W2, W2t);

    // K1: gemm1 (MFMA, BK=64, swizzled LDS) interleaved with pass A binning
    gemm1_passA<<<GEMM1_NB + NB_A, 1024, 0, stream>>>(ei, bin_cursor, ebin, x, W1t, H);

    // K2: per-bin hist + scan + offr/dinv + counting sort -> erec4 (4B/edge)
    buildK2<<<NBINS, 1024, 0, stream>>>(ebin, bin_cursor, offr, dinv, erec4);

    // K3: FUSED layer-1 gather + layer-2 GEMM -> H2a/H2b (split tables)
    agg1_gemm2<<<(NN + 127) / 128, 1024, 0, stream>>>(offr, erec4, dinv, H, b1, W2t, H2a, H2b);

    // K4: layer-2 gather (8 lanes/node) + self + bias + log_softmax -> out
    {
        long long threads = (long long)NN * 8;
        agg2_lsm<<<(unsigned)((threads + 255) / 256), 256, 0, stream>>>(
            offr, erec4, dinv, H2a, H2b, b2, out);
    }
}